// Round 20
// baseline (74.066 us; speedup 1.0000x reference)
//
#include <hip/hip_runtime.h>
#include <hip/hip_bf16.h>

#define E 1024
#define F 12
#define BM 16   // rows per tile

typedef float f32x4_t __attribute__((ext_vector_type(4)));
typedef short bf16x8  __attribute__((ext_vector_type(8)));

// float -> bf16 bits (RNE)
__device__ __forceinline__ short f2bf(float f) {
    return (short)__builtin_bit_cast(unsigned short, __float2bfloat16(f));
}

// 4 waves per block; each wave REDUNDANTLY computes the tile's full h/q
// (MFMA util is 0.4% -> free; x re-reads hit L1), then writes a disjoint
// 4-row output slice. ZERO barriers, zero cross-wave traffic, 16 waves/CU.
__global__ __launch_bounds__(256, 4) void ffq_wave4(
    const float* __restrict__ x,
    const float* __restrict__ W1,
    const float* __restrict__ b1,
    const float* __restrict__ theta,
    const float* __restrict__ W2,
    const float* __restrict__ b2,
    float* __restrict__ out, int nrows)
{
    const int tid  = threadIdx.x;
    const int lane = tid & 63;
    const int wave = tid >> 6;     // 0..3: which 4-row output slice this wave owns
    const int g    = lane >> 4;    // k sub-group (A) / C row group
    const int n    = lane & 15;    // A row (m) on loads / C col (f)

    const int row0 = blockIdx.x * BM;
    if (row0 >= nrows) return;

    __shared__ __align__(16) float qsh[4][16][20];   // per-wave q slab (no sharing)

    const int nc = (n < F) ? n : (F - 1);            // clamp: C cols 12..15 unused
    const float b1n = b1[nc], thn = theta[nc];

    // ---------------- phase 1: h = x . W1^T, full K per wave ----------------
    // A slot (g,j) <- x[row0+n][kb*32 + g*8 + j]; B slot (g,j) <- W1[nc][same k].
    // Same (g,j)->k map for A and B => contraction correct for any bijection.
    const int mrow = min(row0 + n, nrows - 1);
    const float* xrow = x  + (size_t)mrow * E + g * 8;
    const float* wrow = W1 + (size_t)nc   * E + g * 8;

    f32x4_t acc0 = {0.f, 0.f, 0.f, 0.f}, acc1 = {0.f, 0.f, 0.f, 0.f};
#pragma unroll
    for (int kb = 0; kb < 32; ++kb) {                // 32 MFMAs, 2 indep chains
        f32x4_t a0 = *reinterpret_cast<const f32x4_t*>(xrow + kb * 32);
        f32x4_t a1 = *reinterpret_cast<const f32x4_t*>(xrow + kb * 32 + 4);
        f32x4_t b0 = *reinterpret_cast<const f32x4_t*>(wrow + kb * 32);
        f32x4_t b1v= *reinterpret_cast<const f32x4_t*>(wrow + kb * 32 + 4);
        bf16x8 af, bfr;
#pragma unroll
        for (int j = 0; j < 4; ++j) {
            af[j]      = f2bf(a0[j]);
            af[j + 4]  = f2bf(a1[j]);
            bfr[j]     = f2bf(b0[j]);
            bfr[j + 4] = f2bf(b1v[j]);
        }
        if (kb & 1) acc1 = __builtin_amdgcn_mfma_f32_16x16x32_bf16(af, bfr, acc1, 0, 0, 0);
        else        acc0 = __builtin_amdgcn_mfma_f32_16x16x32_bf16(af, bfr, acc0, 0, 0, 0);
    }

    // ---- finisher: in-wave; write own slab (same-wave order, NO barrier) ----
    {
        f32x4_t s = acc0 + acc1;
#pragma unroll
        for (int j = 0; j < 4; ++j)
            qsh[wave][g * 4 + j][n] = __cosf(fmaxf(s[j] + b1n, 0.0f) + thn);
    }

    // ------------- phase 2: own 4-row slice, 4 E-chunks per row -------------
#pragma unroll
    for (int c = 0; c < 4; ++c) {
        const int e0 = c * 256 + lane * 4;           // this lane's 4 output cols

        float w2l[48];                               // W2[(e0+j)][f] = w2l[12j+f]
#pragma unroll
        for (int k2 = 0; k2 < 12; ++k2)
            *reinterpret_cast<f32x4_t*>(&w2l[4 * k2]) =
                *reinterpret_cast<const f32x4_t*>(W2 + (size_t)e0 * F + 4 * k2);
        const f32x4_t bias2 = *reinterpret_cast<const f32x4_t*>(b2 + e0);

#pragma unroll
        for (int r = 0; r < 4; ++r) {
            const int m = wave * 4 + r;              // disjoint across waves
            if (row0 + m < nrows) {
                float qf[F];
                *reinterpret_cast<f32x4_t*>(&qf[0]) = *reinterpret_cast<const f32x4_t*>(&qsh[wave][m][0]);
                *reinterpret_cast<f32x4_t*>(&qf[4]) = *reinterpret_cast<const f32x4_t*>(&qsh[wave][m][4]);
                *reinterpret_cast<f32x4_t*>(&qf[8]) = *reinterpret_cast<const f32x4_t*>(&qsh[wave][m][8]);

                f32x4_t o;
#pragma unroll
                for (int j = 0; j < 4; ++j) {
                    float a = bias2[j];
#pragma unroll
                    for (int f = 0; f < F; ++f) a = fmaf(qf[f], w2l[12 * j + f], a);
                    o[j] = a;
                }
                __builtin_nontemporal_store(o,
                    reinterpret_cast<f32x4_t*>(out + (size_t)(row0 + m) * E + e0));
            }
        }
    }
}

extern "C" void kernel_launch(void* const* d_in, const int* in_sizes, int n_in,
                              void* d_out, int out_size, void* d_ws, size_t ws_size,
                              hipStream_t stream)
{
    const float* x     = (const float*)d_in[0];
    const float* W1    = (const float*)d_in[1];
    const float* b1    = (const float*)d_in[2];
    const float* theta = (const float*)d_in[3];
    const float* W2    = (const float*)d_in[4];
    const float* b2    = (const float*)d_in[5];
    float* out = (float*)d_out;

    const int nrows = in_sizes[0] / E;             // B*S = 16384
    const int grid  = (nrows + BM - 1) / BM;       // 1024 blocks, 4 waves each

    ffq_wave4<<<grid, 256, 0, stream>>>(x, W1, b1, theta, W2, b2, out, nrows);
}

// Round 21
// 29.132 us; speedup vs baseline: 2.5424x; 2.5424x over previous
//
#include <hip/hip_runtime.h>
#include <hip/hip_bf16.h>

#define E 1024
#define F 12
#define BM 16   // rows per block

typedef float f32x4_t __attribute__((ext_vector_type(4)));
typedef short bf16x8  __attribute__((ext_vector_type(8)));

// float -> bf16 bits (RNE)
__device__ __forceinline__ short f2bf(float f) {
    return (short)__builtin_bit_cast(unsigned short, __float2bfloat16(f));
}

__global__ __launch_bounds__(256, 4) void ffq_mfma(
    const float* __restrict__ x,
    const float* __restrict__ W1,
    const float* __restrict__ b1,
    const float* __restrict__ theta,
    const float* __restrict__ W2,
    const float* __restrict__ b2,
    float* __restrict__ out, int nrows)
{
    const int tid  = threadIdx.x;
    const int lane = tid & 63;
    const int wave = tid >> 6;     // K-split: wave w covers k in [w*256, (w+1)*256)
    const int g    = lane >> 4;    // k sub-group within the fragment
    const int n    = lane & 15;    // MFMA: A row (m) / B col (f) / C col

    const int row0 = blockIdx.x * BM;
    if (row0 >= nrows) return;

    __shared__ __align__(16) float red[4][64][4];  // per-wave partial C
    __shared__ __align__(16) float qsh[16][20];    // q[m][f], padded row

    const int nc = (n < F) ? n : (F - 1);          // clamp: C cols 12..15 unused
    const float b1n = b1[nc], thn = theta[nc];

    // ---------------- phase 1: h = x . W1^T via MFMA ----------------
    // A slot (g,j) <- x[row0+n][kb + g*8 + j]; B slot (g,j) <- W1[nc][same k].
    // Same (g,j)->k map for A and B => contraction correct for any bijection.
    const int mrow = min(row0 + n, nrows - 1);
    const float* xrow = x  + (size_t)mrow * E + wave * 256 + g * 8;
    const float* wrow = W1 + (size_t)nc   * E + wave * 256 + g * 8;

    // ---- batched loads: all 16 x-loads + first 8 W1-loads, then fence ----
    f32x4_t xa[16];
#pragma unroll
    for (int ks = 0; ks < 8; ++ks) {
        xa[2 * ks]     = *reinterpret_cast<const f32x4_t*>(xrow + ks * 32);
        xa[2 * ks + 1] = *reinterpret_cast<const f32x4_t*>(xrow + ks * 32 + 4);
    }
    f32x4_t wa[8];
#pragma unroll
    for (int ks = 0; ks < 4; ++ks) {
        wa[2 * ks]     = *reinterpret_cast<const f32x4_t*>(wrow + ks * 32);
        wa[2 * ks + 1] = *reinterpret_cast<const f32x4_t*>(wrow + ks * 32 + 4);
    }
    __builtin_amdgcn_sched_barrier(0);   // loads stay batched above this line

    f32x4_t acc0 = {0.f, 0.f, 0.f, 0.f}, acc1 = {0.f, 0.f, 0.f, 0.f};
#pragma unroll
    for (int ks = 0; ks < 4; ++ks) {
        bf16x8 af, bfr;
#pragma unroll
        for (int j = 0; j < 4; ++j) {
            af[j]      = f2bf(xa[2 * ks][j]);
            af[j + 4]  = f2bf(xa[2 * ks + 1][j]);
            bfr[j]     = f2bf(wa[2 * ks][j]);
            bfr[j + 4] = f2bf(wa[2 * ks + 1][j]);
        }
        if (ks & 1) acc1 = __builtin_amdgcn_mfma_f32_16x16x32_bf16(af, bfr, acc1, 0, 0, 0);
        else        acc0 = __builtin_amdgcn_mfma_f32_16x16x32_bf16(af, bfr, acc0, 0, 0, 0);
    }
    __builtin_amdgcn_sched_barrier(0);

    // ---- second W1 half (reuses wa registers), then remaining MFMAs ----
#pragma unroll
    for (int ks = 0; ks < 4; ++ks) {
        wa[2 * ks]     = *reinterpret_cast<const f32x4_t*>(wrow + (ks + 4) * 32);
        wa[2 * ks + 1] = *reinterpret_cast<const f32x4_t*>(wrow + (ks + 4) * 32 + 4);
    }
    __builtin_amdgcn_sched_barrier(0);

#pragma unroll
    for (int ks = 0; ks < 4; ++ks) {
        bf16x8 af, bfr;
#pragma unroll
        for (int j = 0; j < 4; ++j) {
            af[j]      = f2bf(xa[2 * (ks + 4)][j]);
            af[j + 4]  = f2bf(xa[2 * (ks + 4) + 1][j]);
            bfr[j]     = f2bf(wa[2 * ks][j]);
            bfr[j + 4] = f2bf(wa[2 * ks + 1][j]);
        }
        if (ks & 1) acc1 = __builtin_amdgcn_mfma_f32_16x16x32_bf16(af, bfr, acc1, 0, 0, 0);
        else        acc0 = __builtin_amdgcn_mfma_f32_16x16x32_bf16(af, bfr, acc0, 0, 0, 0);
    }

    *reinterpret_cast<f32x4_t*>(&red[wave][lane][0]) = acc0 + acc1;

    __syncthreads();   // the only block barrier

    // ---- epilogue operands (L2-resident) ----
    float w2l[48];                 // W2[(4t+j)][f] = w2l[12j+f]
#pragma unroll
    for (int k2 = 0; k2 < 12; ++k2)
        *reinterpret_cast<f32x4_t*>(&w2l[4 * k2]) =
            *reinterpret_cast<const f32x4_t*>(W2 + (size_t)tid * 48 + 4 * k2);
    const f32x4_t bias2 = *reinterpret_cast<const f32x4_t*>(b2 + tid * 4);

    // ---- finisher: every wave computes the full 16x16 q tile identically
    //      (same LDS inputs, same order -> bitwise-identical; benign race) ----
    {
        f32x4_t r0 = *reinterpret_cast<const f32x4_t*>(&red[0][lane][0]);
        f32x4_t r1 = *reinterpret_cast<const f32x4_t*>(&red[1][lane][0]);
        f32x4_t r2 = *reinterpret_cast<const f32x4_t*>(&red[2][lane][0]);
        f32x4_t r3 = *reinterpret_cast<const f32x4_t*>(&red[3][lane][0]);
        f32x4_t s  = (r0 + r1) + (r2 + r3);
#pragma unroll
        for (int j = 0; j < 4; ++j) {
            const int m = g * 4 + j;            // C row (HW-verified C/D layout)
            qsh[m][n] = __cosf(fmaxf(s[j] + b1n, 0.0f) + thn);
        }
    }
    // phase2 reads qsh written by this same wave (program order) -> no 2nd barrier

    // ---------------- phase 2: out = q . W2^T + b2 (nontemporal stores) ------
    float* orow = out + (size_t)row0 * E + tid * 4;
#pragma unroll 4
    for (int m = 0; m < BM; ++m) {
        if (row0 + m < nrows) {
            float qf[F];
            *reinterpret_cast<f32x4_t*>(&qf[0]) = *reinterpret_cast<const f32x4_t*>(&qsh[m][0]);
            *reinterpret_cast<f32x4_t*>(&qf[4]) = *reinterpret_cast<const f32x4_t*>(&qsh[m][4]);
            *reinterpret_cast<f32x4_t*>(&qf[8]) = *reinterpret_cast<const f32x4_t*>(&qsh[m][8]);

            f32x4_t o;
#pragma unroll
            for (int j = 0; j < 4; ++j) {
                float a = bias2[j];
#pragma unroll
                for (int f = 0; f < F; ++f) a = fmaf(qf[f], w2l[12 * j + f], a);
                o[j] = a;
            }
            __builtin_nontemporal_store(o, reinterpret_cast<f32x4_t*>(orow + (size_t)m * E));
        }
    }
}

extern "C" void kernel_launch(void* const* d_in, const int* in_sizes, int n_in,
                              void* d_out, int out_size, void* d_ws, size_t ws_size,
                              hipStream_t stream)
{
    const float* x     = (const float*)d_in[0];
    const float* W1    = (const float*)d_in[1];
    const float* b1    = (const float*)d_in[2];
    const float* theta = (const float*)d_in[3];
    const float* W2    = (const float*)d_in[4];
    const float* b2    = (const float*)d_in[5];
    float* out = (float*)d_out;

    const int nrows = in_sizes[0] / E;             // B*S = 16384
    const int grid  = (nrows + BM - 1) / BM;       // 1024 blocks, 4 per CU

    ffq_mfma<<<grid, 256, 0, stream>>>(x, W1, b1, theta, W2, b2, out, nrows);
}